// Round 3
// baseline (1307.894 us; speedup 1.0000x reference)
//
#include <hip/hip_runtime.h>
#include <math.h>

// ---------------------------------------------------------------------------
// SVTR local attention, fp32 baseline.
//   x[64,512,256] -> qkv GEMM -> local attn (7x11 window on 8x64 grid) -> proj
// ws layout: qkv [32768*768] fp32 (100.7MB) | attn_out [32768*256] fp32 (33.5MB)
// ---------------------------------------------------------------------------

#define TILE 128
#define BK 16
#define SCALE_F 0.17677669529663687f  // 32^-0.5

// C[M][N] = A[M][K] * B[N][K]^T (+ bias[N]); M,N multiples of 128, K mult of 16.
__global__ __launch_bounds__(256, 2) void gemm_nt_bias(
    const float* __restrict__ A,
    const float* __restrict__ B,
    const float* __restrict__ bias,
    float* __restrict__ C,
    int M, int N, int K)
{
    __shared__ float As[2][BK][TILE + 4];
    __shared__ float Bs[2][BK][TILE + 4];

    const int tid = threadIdx.x;
    const int m0 = blockIdx.y * TILE;
    const int n0 = blockIdx.x * TILE;

    const int tx = tid & 15;
    const int ty = tid >> 4;

    float acc[2][2][4][4];
#pragma unroll
    for (int p = 0; p < 2; ++p)
#pragma unroll
        for (int q = 0; q < 2; ++q)
#pragma unroll
            for (int i = 0; i < 4; ++i)
#pragma unroll
                for (int j = 0; j < 4; ++j) acc[p][q][i][j] = 0.f;

    // staging: 2 float4 per tile per thread
    const int sm0 = tid >> 2;        // 0..63
    const int sk0 = (tid & 3) * 4;   // 0,4,8,12
    const int sm1 = sm0 + 64;

    const float* Ag0 = A + (size_t)(m0 + sm0) * K + sk0;
    const float* Ag1 = A + (size_t)(m0 + sm1) * K + sk0;
    const float* Bg0 = B + (size_t)(n0 + sm0) * K + sk0;
    const float* Bg1 = B + (size_t)(n0 + sm1) * K + sk0;

    float4 ar0 = *(const float4*)(Ag0);
    float4 ar1 = *(const float4*)(Ag1);
    float4 br0 = *(const float4*)(Bg0);
    float4 br1 = *(const float4*)(Bg1);
#pragma unroll
    for (int j = 0; j < 4; ++j) {
        As[0][sk0 + j][sm0] = ((const float*)&ar0)[j];
        As[0][sk0 + j][sm1] = ((const float*)&ar1)[j];
        Bs[0][sk0 + j][sm0] = ((const float*)&br0)[j];
        Bs[0][sk0 + j][sm1] = ((const float*)&br1)[j];
    }
    __syncthreads();

    const int NTK = K / BK;
    for (int kt = 0; kt < NTK; ++kt) {
        const int cur = kt & 1;
        if (kt + 1 < NTK) {
            const int off = (kt + 1) * BK;
            ar0 = *(const float4*)(Ag0 + off);
            ar1 = *(const float4*)(Ag1 + off);
            br0 = *(const float4*)(Bg0 + off);
            br1 = *(const float4*)(Bg1 + off);
        }
#pragma unroll
        for (int kk = 0; kk < BK; ++kk) {
            float4 a0 = *(const float4*)&As[cur][kk][ty * 4];
            float4 a1 = *(const float4*)&As[cur][kk][64 + ty * 4];
            float4 b0 = *(const float4*)&Bs[cur][kk][tx * 4];
            float4 b1 = *(const float4*)&Bs[cur][kk][64 + tx * 4];
#pragma unroll
            for (int i = 0; i < 4; ++i) {
                const float av0 = ((const float*)&a0)[i];
                const float av1 = ((const float*)&a1)[i];
#pragma unroll
                for (int j = 0; j < 4; ++j) {
                    const float bv0 = ((const float*)&b0)[j];
                    const float bv1 = ((const float*)&b1)[j];
                    acc[0][0][i][j] += av0 * bv0;
                    acc[0][1][i][j] += av0 * bv1;
                    acc[1][0][i][j] += av1 * bv0;
                    acc[1][1][i][j] += av1 * bv1;
                }
            }
        }  // kk
        if (kt + 1 < NTK) {
            const int nxt = cur ^ 1;
#pragma unroll
            for (int j = 0; j < 4; ++j) {
                As[nxt][sk0 + j][sm0] = ((const float*)&ar0)[j];
                As[nxt][sk0 + j][sm1] = ((const float*)&ar1)[j];
                Bs[nxt][sk0 + j][sm0] = ((const float*)&br0)[j];
                Bs[nxt][sk0 + j][sm1] = ((const float*)&br1)[j];
            }
        }
        __syncthreads();
    }  // kt

    float bv[2][4];
#pragma unroll
    for (int q = 0; q < 2; ++q)
#pragma unroll
        for (int j = 0; j < 4; ++j) bv[q][j] = 0.f;
    if (bias != nullptr) {
        float4 t0 = *(const float4*)(bias + n0 + tx * 4);
        float4 t1 = *(const float4*)(bias + n0 + 64 + tx * 4);
#pragma unroll
        for (int j = 0; j < 4; ++j) { bv[0][j] = ((const float*)&t0)[j]; bv[1][j] = ((const float*)&t1)[j]; }
    }

#pragma unroll
    for (int p = 0; p < 2; ++p) {
#pragma unroll
        for (int i = 0; i < 4; ++i) {
            const int row = m0 + p * 64 + ty * 4 + i;
#pragma unroll
            for (int q = 0; q < 2; ++q) {
                float4 o;
                o.x = acc[p][q][i][0] + bv[q][0];
                o.y = acc[p][q][i][1] + bv[q][1];
                o.z = acc[p][q][i][2] + bv[q][2];
                o.w = acc[p][q][i][3] + bv[q][3];
                *(float4*)(C + (size_t)row * N + n0 + q * 64 + tx * 4) = o;
            }
        }
    }
}

// One block per (b, h). 8 waves: wave qh handles query grid-row qh (64 queries).
// Key rows streamed through LDS (double-buffered), transposed [d][c] layout.
__global__ __launch_bounds__(512, 4) void attn_local(
    const float* __restrict__ qkv,      // [B*512][768] (q|k|v, each [8 heads][32])
    float* __restrict__ attn_out)       // [B*512][256], channel = h*32+d
{
    __shared__ float Kt[2][32][65];
    __shared__ float Vt[2][32][65];

    const int h = blockIdx.x;    // head 0..7
    const int b = blockIdx.y;    // batch 0..63
    const int tid = threadIdx.x;
    const int qh = tid >> 6;     // wave id == query grid-row
    const int w = tid & 63;      // query grid-col

    const int sc = tid >> 3;          // staging: pos within row (0..63)
    const int sd = (tid & 7) * 4;     // staging: d offset (0,4,...,28)

    const size_t rowbase = (size_t)b * 512 * 768;

    // q (pre-scaled)
    const float* qp = qkv + rowbase + (size_t)(qh * 64 + w) * 768 + h * 32;
    float q[32];
#pragma unroll
    for (int d4 = 0; d4 < 8; ++d4) {
        float4 v = *(const float4*)(qp + d4 * 4);
        q[d4 * 4 + 0] = v.x * SCALE_F;
        q[d4 * 4 + 1] = v.y * SCALE_F;
        q[d4 * 4 + 2] = v.z * SCALE_F;
        q[d4 * 4 + 3] = v.w * SCALE_F;
    }

    float mrun = -INFINITY, lrun = 0.f;
    float outv[32];
#pragma unroll
    for (int d = 0; d < 32; ++d) outv[d] = 0.f;

    const int r0 = (qh - 3 < 0) ? 0 : qh - 3;
    const int r1 = (qh + 3 > 7) ? 7 : qh + 3;

    // stage key-row 0 into buffer 0
    {
        const float* sp = qkv + rowbase + (size_t)(sc)*768 + h * 32 + sd;
        float4 kv = *(const float4*)(sp + 256);
        float4 vv = *(const float4*)(sp + 512);
#pragma unroll
        for (int j = 0; j < 4; ++j) {
            Kt[0][sd + j][sc] = ((const float*)&kv)[j];
            Vt[0][sd + j][sc] = ((const float*)&vv)[j];
        }
    }
    __syncthreads();

    for (int r = 0; r < 8; ++r) {
        const int cur = r & 1;
        float4 kv, vv;
        if (r < 7) {  // issue next-row loads early; write to LDS after compute
            const float* sp = qkv + rowbase + (size_t)((r + 1) * 64 + sc) * 768 + h * 32 + sd;
            kv = *(const float4*)(sp + 256);
            vv = *(const float4*)(sp + 512);
        }
        if (r >= r0 && r <= r1) {   // wave-uniform predicate
            float p[11];
            int cc[11];
            float rowmax = -INFINITY;
#pragma unroll
            for (int dc = 0; dc < 11; ++dc) {
                const int c = w + dc - 5;
                const bool valid = (c >= 0) && (c < 64);
                const int cl = c < 0 ? 0 : (c > 63 ? 63 : c);
                cc[dc] = cl;
                float acc = 0.f;
#pragma unroll
                for (int d = 0; d < 32; ++d) acc += q[d] * Kt[cur][d][cl];
                p[dc] = valid ? acc : -INFINITY;
                rowmax = fmaxf(rowmax, p[dc]);
            }
            const float mnew = fmaxf(mrun, rowmax);
            const float scl = __expf(mrun - mnew);   // first row: exp(-inf)=0
            float lsum = 0.f;
#pragma unroll
            for (int dc = 0; dc < 11; ++dc) {
                p[dc] = __expf(p[dc] - mnew);        // invalid: exp(-inf)=0
                lsum += p[dc];
            }
            lrun = lrun * scl + lsum;
#pragma unroll
            for (int d = 0; d < 32; ++d) {
                float t = 0.f;
#pragma unroll
                for (int dc = 0; dc < 11; ++dc) t += p[dc] * Vt[cur][d][cc[dc]];
                outv[d] = outv[d] * scl + t;
            }
            mrun = mnew;
        }
        if (r < 7) {
            const int nxt = cur ^ 1;
#pragma unroll
            for (int j = 0; j < 4; ++j) {
                Kt[nxt][sd + j][sc] = ((const float*)&kv)[j];
                Vt[nxt][sd + j][sc] = ((const float*)&vv)[j];
            }
        }
        __syncthreads();
    }

    const float inv = 1.f / lrun;
    float* op = attn_out + (size_t)(b * 512 + qh * 64 + w) * 256 + h * 32;
#pragma unroll
    for (int d4 = 0; d4 < 8; ++d4) {
        float4 v;
        v.x = outv[d4 * 4 + 0] * inv;
        v.y = outv[d4 * 4 + 1] * inv;
        v.z = outv[d4 * 4 + 2] * inv;
        v.w = outv[d4 * 4 + 3] * inv;
        *(float4*)(op + d4 * 4) = v;
    }
}

extern "C" void kernel_launch(void* const* d_in, const int* in_sizes, int n_in,
                              void* d_out, int out_size, void* d_ws, size_t ws_size,
                              hipStream_t stream)
{
    const float* x      = (const float*)d_in[0];   // [64,512,256]
    const float* w_qkv  = (const float*)d_in[1];   // [768,256]
    const float* w_proj = (const float*)d_in[2];   // [256,256]
    const float* b_proj = (const float*)d_in[3];   // [256]
    float* out = (float*)d_out;                    // [64,512,256]

    float* qkv  = (float*)d_ws;                    // [32768][768]
    float* attn = qkv + (size_t)32768 * 768;       // [32768][256]

    const int M = 32768, K = 256;

    // 1) qkv = x @ w_qkv^T
    dim3 g1(768 / TILE, M / TILE);
    gemm_nt_bias<<<g1, 256, 0, stream>>>(x, w_qkv, nullptr, qkv, M, 768, K);

    // 2) local-window attention
    attn_local<<<dim3(8, 64), 512, 0, stream>>>(qkv, attn);

    // 3) out = attn @ w_proj^T + b_proj
    dim3 g3(256 / TILE, M / TILE);
    gemm_nt_bias<<<g3, 256, 0, stream>>>(attn, w_proj, b_proj, out, M, 256, K);
}

// Round 6
// 307.264 us; speedup vs baseline: 4.2566x; 4.2566x over previous
//
#include <hip/hip_runtime.h>
#include <math.h>

// ---------------------------------------------------------------------------
// SVTR local attention.
//   x[64,512,256] -> qkv GEMM (bf16x3 MFMA) -> local attn (7x11 win, fp32)
//   -> proj GEMM (bf16x3 MFMA)
// ws: qkv [32768*768] fp32 (100.7MB) | attn_out [32768*256] fp32 (33.5MB)
// bf16x3: a = hi + lo (two bf16), C = Ah*Bh + Ah*Bl + Al*Bh  (~1e-4 rel err)
// ---------------------------------------------------------------------------

#define SCALE_F 0.17677669529663687f  // 32^-0.5
#define GK 256                        // K for both GEMMs
#define KC 128                        // K chunk staged in LDS
#define LDB 136                       // bf16 elems per LDS row (128 + 8 pad)

typedef __attribute__((ext_vector_type(8))) short bf16x8;
typedef __attribute__((ext_vector_type(4))) float f32x4;

// split fp32 into hi (truncated bf16) + lo (RNE bf16 of exact residual)
__device__ __forceinline__ void splitf(float a, short& hi, short& lo) {
    unsigned u = __builtin_bit_cast(unsigned, a);
    unsigned uh = u & 0xffff0000u;
    hi = (short)(uh >> 16);
    float r = a - __builtin_bit_cast(float, uh);   // exact
    unsigned ur = __builtin_bit_cast(unsigned, r);
    ur += 0x7fffu + ((ur >> 16) & 1u);             // RNE to bf16
    lo = (short)(ur >> 16);
}

// C[M][N] = A[M][256] * B[N][256]^T (+bias), bf16x3 via MFMA 16x16x32.
// grid: (N/64, M/64), block 256 (4 waves); wave w owns rows w*16..w*16+15.
__global__ __launch_bounds__(256) void gemm_nt_mfma(
    const float* __restrict__ A,
    const float* __restrict__ B,
    const float* __restrict__ bias,
    float* __restrict__ C,
    int M, int N)
{
    __shared__ short Ah[64 * LDB], Al[64 * LDB], Bh[64 * LDB], Bl[64 * LDB];

    const int tid = threadIdx.x;
    const int n0 = blockIdx.x * 64;
    const int m0 = blockIdx.y * 64;

    const int wid  = tid >> 6;
    const int lane = tid & 63;
    const int fr = lane & 15;   // frag row (m or n within 16-tile)
    const int fq = lane >> 4;   // k-group: k offset = fq*8

    f32x4 acc[4];
#pragma unroll
    for (int nt = 0; nt < 4; ++nt) acc[nt] = (f32x4){0.f, 0.f, 0.f, 0.f};

    for (int kc = 0; kc < 2; ++kc) {
        if (kc) __syncthreads();  // protect LDS before restage
        // stage+split this K-chunk: A[64][128], B[64][128] -> hi/lo bf16 LDS
#pragma unroll
        for (int i = 0; i < 8; ++i) {
            const int idx = i * 256 + tid;
            const int row = idx >> 5;        // 0..63
            const int c4  = idx & 31;        // float4 index within row
            const float4 va = *(const float4*)(A + (size_t)(m0 + row) * GK + kc * KC + c4 * 4);
            const float4 vb = *(const float4*)(B + (size_t)(n0 + row) * GK + kc * KC + c4 * 4);
            short h0, h1, h2, h3, l0, l1, l2, l3;
            splitf(va.x, h0, l0); splitf(va.y, h1, l1);
            splitf(va.z, h2, l2); splitf(va.w, h3, l3);
            int2 ph, pl;
            ph.x = (int)(unsigned short)h0 | ((int)h1 << 16);
            ph.y = (int)(unsigned short)h2 | ((int)h3 << 16);
            pl.x = (int)(unsigned short)l0 | ((int)l1 << 16);
            pl.y = (int)(unsigned short)l2 | ((int)l3 << 16);
            *(int2*)&Ah[row * LDB + c4 * 4] = ph;
            *(int2*)&Al[row * LDB + c4 * 4] = pl;
            splitf(vb.x, h0, l0); splitf(vb.y, h1, l1);
            splitf(vb.z, h2, l2); splitf(vb.w, h3, l3);
            ph.x = (int)(unsigned short)h0 | ((int)h1 << 16);
            ph.y = (int)(unsigned short)h2 | ((int)h3 << 16);
            pl.x = (int)(unsigned short)l0 | ((int)l1 << 16);
            pl.y = (int)(unsigned short)l2 | ((int)l3 << 16);
            *(int2*)&Bh[row * LDB + c4 * 4] = ph;
            *(int2*)&Bl[row * LDB + c4 * 4] = pl;
        }
        __syncthreads();

        // A frags for this wave's 16 rows, all 4 k-tiles of the chunk
        bf16x8 ah[4], al[4];
#pragma unroll
        for (int kt = 0; kt < 4; ++kt) {
            const int off = (wid * 16 + fr) * LDB + kt * 32 + fq * 8;
            ah[kt] = *(const bf16x8*)&Ah[off];
            al[kt] = *(const bf16x8*)&Al[off];
        }
#pragma unroll
        for (int nt = 0; nt < 4; ++nt) {
#pragma unroll
            for (int kt = 0; kt < 4; ++kt) {
                const int off = (nt * 16 + fr) * LDB + kt * 32 + fq * 8;
                const bf16x8 bh = *(const bf16x8*)&Bh[off];
                const bf16x8 bl = *(const bf16x8*)&Bl[off];
                acc[nt] = __builtin_amdgcn_mfma_f32_16x16x32_bf16(al[kt], bh, acc[nt], 0, 0, 0);
                acc[nt] = __builtin_amdgcn_mfma_f32_16x16x32_bf16(ah[kt], bl, acc[nt], 0, 0, 0);
                acc[nt] = __builtin_amdgcn_mfma_f32_16x16x32_bf16(ah[kt], bh, acc[nt], 0, 0, 0);
            }
        }
    }

    // epilogue: D lane mapping col=lane&15, row=(lane>>4)*4+i  [m89]
#pragma unroll
    for (int nt = 0; nt < 4; ++nt) {
        const int col = n0 + nt * 16 + fr;
        const float bv = bias ? bias[col] : 0.f;
#pragma unroll
        for (int i = 0; i < 4; ++i) {
            const int row = m0 + wid * 16 + fq * 4 + i;
            C[(size_t)row * N + col] = acc[nt][i] + bv;
        }
    }
}

// One block per (b, h). 8 waves: wave qh handles query grid-row qh (64 queries).
// Key rows streamed through LDS (double-buffered), transposed [d][c] layout.
__global__ __launch_bounds__(512, 4) void attn_local(
    const float* __restrict__ qkv,      // [B*512][768] (q|k|v, each [8 heads][32])
    float* __restrict__ attn_out)       // [B*512][256], channel = h*32+d
{
    __shared__ float Kt[2][32][65];
    __shared__ float Vt[2][32][65];

    const int h = blockIdx.x;    // head 0..7
    const int b = blockIdx.y;    // batch 0..63
    const int tid = threadIdx.x;
    const int qh = tid >> 6;     // wave id == query grid-row
    const int w = tid & 63;      // query grid-col

    const int sc = tid >> 3;          // staging: pos within row (0..63)
    const int sd = (tid & 7) * 4;     // staging: d offset (0,4,...,28)

    const size_t rowbase = (size_t)b * 512 * 768;

    const float* qp = qkv + rowbase + (size_t)(qh * 64 + w) * 768 + h * 32;
    float q[32];
#pragma unroll
    for (int d4 = 0; d4 < 8; ++d4) {
        float4 v = *(const float4*)(qp + d4 * 4);
        q[d4 * 4 + 0] = v.x * SCALE_F;
        q[d4 * 4 + 1] = v.y * SCALE_F;
        q[d4 * 4 + 2] = v.z * SCALE_F;
        q[d4 * 4 + 3] = v.w * SCALE_F;
    }

    float mrun = -INFINITY, lrun = 0.f;
    float outv[32];
#pragma unroll
    for (int d = 0; d < 32; ++d) outv[d] = 0.f;

    const int r0 = (qh - 3 < 0) ? 0 : qh - 3;
    const int r1 = (qh + 3 > 7) ? 7 : qh + 3;

    {
        const float* sp = qkv + rowbase + (size_t)(sc)*768 + h * 32 + sd;
        float4 kv = *(const float4*)(sp + 256);
        float4 vv = *(const float4*)(sp + 512);
#pragma unroll
        for (int j = 0; j < 4; ++j) {
            Kt[0][sd + j][sc] = ((const float*)&kv)[j];
            Vt[0][sd + j][sc] = ((const float*)&vv)[j];
        }
    }
    __syncthreads();

    for (int r = 0; r < 8; ++r) {
        const int cur = r & 1;
        float4 kv, vv;
        if (r < 7) {
            const float* sp = qkv + rowbase + (size_t)((r + 1) * 64 + sc) * 768 + h * 32 + sd;
            kv = *(const float4*)(sp + 256);
            vv = *(const float4*)(sp + 512);
        }
        if (r >= r0 && r <= r1) {   // wave-uniform predicate
            float p[11];
            int cc[11];
            float rowmax = -INFINITY;
#pragma unroll
            for (int dc = 0; dc < 11; ++dc) {
                const int c = w + dc - 5;
                const bool valid = (c >= 0) && (c < 64);
                const int cl = c < 0 ? 0 : (c > 63 ? 63 : c);
                cc[dc] = cl;
                float acc = 0.f;
#pragma unroll
                for (int d = 0; d < 32; ++d) acc += q[d] * Kt[cur][d][cl];
                p[dc] = valid ? acc : -INFINITY;
                rowmax = fmaxf(rowmax, p[dc]);
            }
            const float mnew = fmaxf(mrun, rowmax);
            const float scl = __expf(mrun - mnew);
            float lsum = 0.f;
#pragma unroll
            for (int dc = 0; dc < 11; ++dc) {
                p[dc] = __expf(p[dc] - mnew);
                lsum += p[dc];
            }
            lrun = lrun * scl + lsum;
#pragma unroll
            for (int d = 0; d < 32; ++d) {
                float t = 0.f;
#pragma unroll
                for (int dc = 0; dc < 11; ++dc) t += p[dc] * Vt[cur][d][cc[dc]];
                outv[d] = outv[d] * scl + t;
            }
            mrun = mnew;
        }
        if (r < 7) {
            const int nxt = cur ^ 1;
#pragma unroll
            for (int j = 0; j < 4; ++j) {
                Kt[nxt][sd + j][sc] = ((const float*)&kv)[j];
                Vt[nxt][sd + j][sc] = ((const float*)&vv)[j];
            }
        }
        __syncthreads();
    }

    const float inv = 1.f / lrun;
    float* op = attn_out + (size_t)(b * 512 + qh * 64 + w) * 256 + h * 32;
#pragma unroll
    for (int d4 = 0; d4 < 8; ++d4) {
        float4 v;
        v.x = outv[d4 * 4 + 0] * inv;
        v.y = outv[d4 * 4 + 1] * inv;
        v.z = outv[d4 * 4 + 2] * inv;
        v.w = outv[d4 * 4 + 3] * inv;
        *(float4*)(op + d4 * 4) = v;
    }
}

extern "C" void kernel_launch(void* const* d_in, const int* in_sizes, int n_in,
                              void* d_out, int out_size, void* d_ws, size_t ws_size,
                              hipStream_t stream)
{
    const float* x      = (const float*)d_in[0];   // [64,512,256]
    const float* w_qkv  = (const float*)d_in[1];   // [768,256]
    const float* w_proj = (const float*)d_in[2];   // [256,256]
    const float* b_proj = (const float*)d_in[3];   // [256]
    float* out = (float*)d_out;                    // [64,512,256]

    float* qkv  = (float*)d_ws;                    // [32768][768]
    float* attn = qkv + (size_t)32768 * 768;       // [32768][256]

    const int M = 32768;

    // 1) qkv = x @ w_qkv^T   (bf16x3 MFMA)
    gemm_nt_mfma<<<dim3(768 / 64, M / 64), 256, 0, stream>>>(x, w_qkv, nullptr, qkv, M, 768);

    // 2) local-window attention (fp32)
    attn_local<<<dim3(8, 64), 512, 0, stream>>>(qkv, attn);

    // 3) out = attn @ w_proj^T + b_proj   (bf16x3 MFMA)
    gemm_nt_mfma<<<dim3(256 / 64, M / 64), 256, 0, stream>>>(attn, w_proj, b_proj, out, M, 256);
}

// Round 8
// 276.644 us; speedup vs baseline: 4.7277x; 1.1107x over previous
//
#include <hip/hip_runtime.h>
#include <math.h>

// ---------------------------------------------------------------------------
// SVTR local attention.
//   x[64,512,256] -> qkv GEMM (bf16x3 MFMA) -> local attn (7x11 win, MFMA)
//   -> proj GEMM (bf16x3 MFMA)
// ws: qkv [32768*768] fp32 (100.7MB) | attn_out [32768*256] fp32 (33.5MB)
// bf16x3: a = hi + lo (two bf16), C = Ah*Bh + Ah*Bl + Al*Bh  (~1e-4 rel err)
// ---------------------------------------------------------------------------

#define SCALE_F 0.17677669529663687f  // 32^-0.5
#define GK 256                        // K for both GEMMs
#define KC 128                        // K chunk staged in LDS
#define LDB 136                       // bf16 elems per LDS row (128 + 8 pad)

typedef __attribute__((ext_vector_type(8))) short bf16x8;
typedef __attribute__((ext_vector_type(4))) float f32x4;

// split fp32 into hi (truncated bf16) + lo (RNE bf16 of exact residual)
__device__ __forceinline__ void splitf(float a, short& hi, short& lo) {
    unsigned u = __builtin_bit_cast(unsigned, a);
    unsigned uh = u & 0xffff0000u;
    hi = (short)(uh >> 16);
    float r = a - __builtin_bit_cast(float, uh);   // exact
    unsigned ur = __builtin_bit_cast(unsigned, r);
    ur += 0x7fffu + ((ur >> 16) & 1u);             // RNE to bf16
    lo = (short)(ur >> 16);
}

__device__ __forceinline__ unsigned short bf16rne(float x) {
    unsigned u = __builtin_bit_cast(unsigned, x);
    u += 0x7fffu + ((u >> 16) & 1u);
    return (unsigned short)(u >> 16);
}

// ======================= GEMM (unchanged, verified) ========================
__global__ __launch_bounds__(256) void gemm_nt_mfma(
    const float* __restrict__ A,
    const float* __restrict__ B,
    const float* __restrict__ bias,
    float* __restrict__ C,
    int M, int N)
{
    __shared__ short Ah[64 * LDB], Al[64 * LDB], Bh[64 * LDB], Bl[64 * LDB];

    const int tid = threadIdx.x;
    const int n0 = blockIdx.x * 64;
    const int m0 = blockIdx.y * 64;

    const int wid  = tid >> 6;
    const int lane = tid & 63;
    const int fr = lane & 15;
    const int fq = lane >> 4;

    f32x4 acc[4];
#pragma unroll
    for (int nt = 0; nt < 4; ++nt) acc[nt] = (f32x4){0.f, 0.f, 0.f, 0.f};

    for (int kc = 0; kc < 2; ++kc) {
        if (kc) __syncthreads();
#pragma unroll
        for (int i = 0; i < 8; ++i) {
            const int idx = i * 256 + tid;
            const int row = idx >> 5;
            const int c4  = idx & 31;
            const float4 va = *(const float4*)(A + (size_t)(m0 + row) * GK + kc * KC + c4 * 4);
            const float4 vb = *(const float4*)(B + (size_t)(n0 + row) * GK + kc * KC + c4 * 4);
            short h0, h1, h2, h3, l0, l1, l2, l3;
            splitf(va.x, h0, l0); splitf(va.y, h1, l1);
            splitf(va.z, h2, l2); splitf(va.w, h3, l3);
            int2 ph, pl;
            ph.x = (int)(unsigned short)h0 | ((int)h1 << 16);
            ph.y = (int)(unsigned short)h2 | ((int)h3 << 16);
            pl.x = (int)(unsigned short)l0 | ((int)l1 << 16);
            pl.y = (int)(unsigned short)l2 | ((int)l3 << 16);
            *(int2*)&Ah[row * LDB + c4 * 4] = ph;
            *(int2*)&Al[row * LDB + c4 * 4] = pl;
            splitf(vb.x, h0, l0); splitf(vb.y, h1, l1);
            splitf(vb.z, h2, l2); splitf(vb.w, h3, l3);
            ph.x = (int)(unsigned short)h0 | ((int)h1 << 16);
            ph.y = (int)(unsigned short)h2 | ((int)h3 << 16);
            pl.x = (int)(unsigned short)l0 | ((int)l1 << 16);
            pl.y = (int)(unsigned short)l2 | ((int)l3 << 16);
            *(int2*)&Bh[row * LDB + c4 * 4] = ph;
            *(int2*)&Bl[row * LDB + c4 * 4] = pl;
        }
        __syncthreads();

        bf16x8 ah[4], al[4];
#pragma unroll
        for (int kt = 0; kt < 4; ++kt) {
            const int off = (wid * 16 + fr) * LDB + kt * 32 + fq * 8;
            ah[kt] = *(const bf16x8*)&Ah[off];
            al[kt] = *(const bf16x8*)&Al[off];
        }
#pragma unroll
        for (int nt = 0; nt < 4; ++nt) {
#pragma unroll
            for (int kt = 0; kt < 4; ++kt) {
                const int off = (nt * 16 + fr) * LDB + kt * 32 + fq * 8;
                const bf16x8 bh = *(const bf16x8*)&Bh[off];
                const bf16x8 bl = *(const bf16x8*)&Bl[off];
                acc[nt] = __builtin_amdgcn_mfma_f32_16x16x32_bf16(al[kt], bh, acc[nt], 0, 0, 0);
                acc[nt] = __builtin_amdgcn_mfma_f32_16x16x32_bf16(ah[kt], bl, acc[nt], 0, 0, 0);
                acc[nt] = __builtin_amdgcn_mfma_f32_16x16x32_bf16(ah[kt], bh, acc[nt], 0, 0, 0);
            }
        }
    }

#pragma unroll
    for (int nt = 0; nt < 4; ++nt) {
        const int col = n0 + nt * 16 + fr;
        const float bv = bias ? bias[col] : 0.f;
#pragma unroll
        for (int i = 0; i < 4; ++i) {
            const int row = m0 + wid * 16 + fq * 4 + i;
            C[(size_t)row * N + col] = acc[nt][i] + bv;
        }
    }
}

// ======================= MFMA local attention ==============================
// One block per (b,h). 8 waves; wave qh owns query grid-row qh (64 queries).
// Per key-row r (streamed, dbuf LDS): S'[c][w] = (K hi/lo)·(Q hi/lo)^T via
// 16x16x32 MFMA, band tiles |rt-wt|<=1 only; online softmax (rows on
// lane&15); P->bf16; shuffle-regroup into PV B-frags; O'[d][w] += V^T·P.
// LDS strides: K rows 40 bf16 (80B), Vt rows 72 bf16 -> <=2-way bank alias.
__global__ __launch_bounds__(512) void attn_local_mfma(
    const float* __restrict__ qkv,      // [B*512][768] (q|k|v, each [8 h][32])
    float* __restrict__ attn_out)       // [B*512][256], channel = h*32+d
{
    __shared__ __align__(16) short Kh[2][64 * 40], Kl[2][64 * 40];
    __shared__ __align__(16) short Vh[2][32 * 72], Vl[2][32 * 72];

    const int h = blockIdx.x;
    const int b = blockIdx.y;
    const int tid = threadIdx.x;
    const int qh = tid >> 6;
    const int lane = tid & 63;
    const int w0 = lane & 15;       // frag row/col index
    const int g  = lane >> 4;       // lane group
    const size_t rowbase = (size_t)b * 512 * 768;

    // ---- Q fragments (hi/lo), scale folded in. B-frag: col=w0, k=g*8+j ----
    bf16x8 qfh[4], qfl[4];
#pragma unroll
    for (int wt = 0; wt < 4; ++wt) {
        const float* qp = qkv + rowbase + (size_t)(qh * 64 + wt * 16 + w0) * 768 + h * 32 + g * 8;
        const float4 qa = *(const float4*)qp;
        const float4 qb = *(const float4*)(qp + 4);
        float qv[8] = {qa.x, qa.y, qa.z, qa.w, qb.x, qb.y, qb.z, qb.w};
#pragma unroll
        for (int e = 0; e < 8; ++e) {
            short hh, ll;
            splitf(qv[e] * SCALE_F, hh, ll);
            qfh[wt][e] = hh;
            qfl[wt][e] = ll;
        }
    }

    f32x4 pv[2][4];
#pragma unroll
    for (int mt = 0; mt < 2; ++mt)
#pragma unroll
        for (int wt = 0; wt < 4; ++wt) pv[mt][wt] = (f32x4){0.f, 0.f, 0.f, 0.f};
    float mrun[4] = {-INFINITY, -INFINITY, -INFINITY, -INFINITY};
    float lrun[4] = {0.f, 0.f, 0.f, 0.f};

    // staging coords: thread -> (key col c, dim d0)
    const int sc = tid >> 3;          // 0..63
    const int sd = (tid & 7) * 4;     // 0,4,...,28

    // ---- stage key-row 0 into buffer 0 ----
    {
        const float* sp = qkv + rowbase + (size_t)sc * 768 + h * 32 + sd;
        const float4 kv = *(const float4*)(sp + 256);
        const float4 vv = *(const float4*)(sp + 512);
        const float kvf[4] = {kv.x, kv.y, kv.z, kv.w};
        const float vvf[4] = {vv.x, vv.y, vv.z, vv.w};
        short kh4[4], kl4[4];
#pragma unroll
        for (int j = 0; j < 4; ++j) splitf(kvf[j], kh4[j], kl4[j]);
        int2 ph, pl;
        ph.x = (int)(unsigned short)kh4[0] | ((int)kh4[1] << 16);
        ph.y = (int)(unsigned short)kh4[2] | ((int)kh4[3] << 16);
        pl.x = (int)(unsigned short)kl4[0] | ((int)kl4[1] << 16);
        pl.y = (int)(unsigned short)kl4[2] | ((int)kl4[3] << 16);
        *(int2*)&Kh[0][sc * 40 + sd] = ph;
        *(int2*)&Kl[0][sc * 40 + sd] = pl;
#pragma unroll
        for (int j = 0; j < 4; ++j) {
            short vh_, vl_;
            splitf(vvf[j], vh_, vl_);
            Vh[0][(sd + j) * 72 + sc] = vh_;
            Vl[0][(sd + j) * 72 + sc] = vl_;
        }
    }
    __syncthreads();

    const int r0 = (qh - 3 < 0) ? 0 : qh - 3;
    const int r1 = (qh + 3 > 7) ? 7 : qh + 3;

    for (int r = 0; r < 8; ++r) {
        const int cur = r & 1;
        float4 kvn, vvn;
        if (r < 7) {  // issue next-row loads early
            const float* sp = qkv + rowbase + (size_t)((r + 1) * 64 + sc) * 768 + h * 32 + sd;
            kvn = *(const float4*)(sp + 256);
            vvn = *(const float4*)(sp + 512);
        }

        if (r >= r0 && r <= r1) {   // wave-uniform predicate
            // ---- K A-frags: row c = rt*16+w0, k = d = g*8+j ----
            bf16x8 kfh[4], kfl[4];
#pragma unroll
            for (int rt = 0; rt < 4; ++rt) {
                const int off = (rt * 16 + w0) * 40 + g * 8;
                kfh[rt] = *(const bf16x8*)&Kh[cur][off];
                kfl[rt] = *(const bf16x8*)&Kl[cur][off];
            }

            // ---- S' band tiles: sm[wt][rto], rt = wt-1+rto ----
            f32x4 sm[4][3];
#pragma unroll
            for (int wt = 0; wt < 4; ++wt) {
#pragma unroll
                for (int rto = 0; rto < 3; ++rto) {
                    const int rt = wt - 1 + rto;
                    if (rt < 0 || rt > 3) continue;
                    f32x4 s = (f32x4){0.f, 0.f, 0.f, 0.f};
                    s = __builtin_amdgcn_mfma_f32_16x16x32_bf16(kfl[rt], qfh[wt], s, 0, 0, 0);
                    s = __builtin_amdgcn_mfma_f32_16x16x32_bf16(kfh[rt], qfl[wt], s, 0, 0, 0);
                    s = __builtin_amdgcn_mfma_f32_16x16x32_bf16(kfh[rt], qfh[wt], s, 0, 0, 0);
                    const int wq = wt * 16 + w0;
#pragma unroll
                    for (int i = 0; i < 4; ++i) {
                        const int c = rt * 16 + g * 4 + i;
                        const int d = wq - c;
                        if (d > 5 || d < -5) s[i] = -INFINITY;
                    }
                    sm[wt][rto] = s;
                }
            }

            // ---- online softmax per wt; pack P to bf16 pairs ----
            unsigned pk2[4][3][2];
#pragma unroll
            for (int wt = 0; wt < 4; ++wt) {
                float mt_ = -INFINITY;
#pragma unroll
                for (int rto = 0; rto < 3; ++rto) {
                    const int rt = wt - 1 + rto;
                    if (rt < 0 || rt > 3) continue;
#pragma unroll
                    for (int i = 0; i < 4; ++i) mt_ = fmaxf(mt_, sm[wt][rto][i]);
                }
                mt_ = fmaxf(mt_, __shfl_xor(mt_, 16));
                mt_ = fmaxf(mt_, __shfl_xor(mt_, 32));
                const float mnew = fmaxf(mrun[wt], mt_);
                const float scl = __expf(mrun[wt] - mnew);   // first: exp(-inf)=0
                float ls = 0.f;
#pragma unroll
                for (int rto = 0; rto < 3; ++rto) {
                    const int rt = wt - 1 + rto;
                    if (rt < 0 || rt > 3) continue;
#pragma unroll
                    for (int i = 0; i < 4; ++i) {
                        const float p = __expf(sm[wt][rto][i] - mnew);  // masked: 0
                        sm[wt][rto][i] = p;
                        ls += p;
                    }
                }
                ls += __shfl_xor(ls, 16);
                ls += __shfl_xor(ls, 32);
                lrun[wt] = lrun[wt] * scl + ls;
                mrun[wt] = mnew;
#pragma unroll
                for (int mt = 0; mt < 2; ++mt)
#pragma unroll
                    for (int i = 0; i < 4; ++i) pv[mt][wt][i] *= scl;
#pragma unroll
                for (int rto = 0; rto < 3; ++rto) {
                    const int rt = wt - 1 + rto;
                    if (rt < 0 || rt > 3) continue;
#pragma unroll
                    for (int pi = 0; pi < 2; ++pi)
                        pk2[wt][rto][pi] = (unsigned)bf16rne(sm[wt][rto][2 * pi]) |
                                           ((unsigned)bf16rne(sm[wt][rto][2 * pi + 1]) << 16);
                }
            }

            // ---- PV: O'[d][w] += V^T (hi+lo) · P ----
#pragma unroll
            for (int kt = 0; kt < 2; ++kt) {
                bf16x8 vfh[2], vfl[2];
#pragma unroll
                for (int mt = 0; mt < 2; ++mt) {
                    const int off = (mt * 16 + w0) * 72 + kt * 32 + g * 8;
                    vfh[mt] = *(const bf16x8*)&Vh[cur][off];
                    vfl[mt] = *(const bf16x8*)&Vl[cur][off];
                }
#pragma unroll
                for (int wt = 0; wt < 4; ++wt) {
                    const int rtlo = 2 * kt, rthi = 2 * kt + 1;
                    const bool has_lo = (rtlo - wt <= 1) && (wt - rtlo <= 1);
                    const bool has_hi = (rthi - wt <= 1) && (wt - rthi <= 1);
                    if (!has_lo && !has_hi) continue;
                    int dw[4];
#pragma unroll
                    for (int jd = 0; jd < 4; ++jd) {
                        const int src = (2 * (g & 1) + (jd >> 1)) * 16 + w0;
                        int lo = 0, hi = 0;
                        if (has_lo) lo = __shfl((int)pk2[wt][rtlo - wt + 1][jd & 1], src);
                        if (has_hi) hi = __shfl((int)pk2[wt][rthi - wt + 1][jd & 1], src);
                        dw[jd] = (g < 2) ? lo : hi;
                    }
                    const int4 tmp = {dw[0], dw[1], dw[2], dw[3]};
                    const bf16x8 pf = __builtin_bit_cast(bf16x8, tmp);
#pragma unroll
                    for (int mt = 0; mt < 2; ++mt) {
                        pv[mt][wt] = __builtin_amdgcn_mfma_f32_16x16x32_bf16(vfh[mt], pf, pv[mt][wt], 0, 0, 0);
                        pv[mt][wt] = __builtin_amdgcn_mfma_f32_16x16x32_bf16(vfl[mt], pf, pv[mt][wt], 0, 0, 0);
                    }
                }
            }
        }

        if (r < 7) {  // write next row into other buffer
            const int nxt = cur ^ 1;
            const float kvf[4] = {kvn.x, kvn.y, kvn.z, kvn.w};
            const float vvf[4] = {vvn.x, vvn.y, vvn.z, vvn.w};
            short kh4[4], kl4[4];
#pragma unroll
            for (int j = 0; j < 4; ++j) splitf(kvf[j], kh4[j], kl4[j]);
            int2 ph, pl;
            ph.x = (int)(unsigned short)kh4[0] | ((int)kh4[1] << 16);
            ph.y = (int)(unsigned short)kh4[2] | ((int)kh4[3] << 16);
            pl.x = (int)(unsigned short)kl4[0] | ((int)kl4[1] << 16);
            pl.y = (int)(unsigned short)kl4[2] | ((int)kl4[3] << 16);
            *(int2*)&Kh[nxt][sc * 40 + sd] = ph;
            *(int2*)&Kl[nxt][sc * 40 + sd] = pl;
#pragma unroll
            for (int j = 0; j < 4; ++j) {
                short vh_, vl_;
                splitf(vvf[j], vh_, vl_);
                Vh[nxt][(sd + j) * 72 + sc] = vh_;
                Vl[nxt][(sd + j) * 72 + sc] = vl_;
            }
        }
        __syncthreads();
    }

    // ---- epilogue: out[w][d] = O'[d][w] / l[w] ----
#pragma unroll
    for (int wt = 0; wt < 4; ++wt) {
        const float inv = 1.f / lrun[wt];
        float* op = attn_out + (size_t)(b * 512 + qh * 64 + wt * 16 + w0) * 256 + h * 32;
#pragma unroll
        for (int mt = 0; mt < 2; ++mt) {
            float4 o;
            o.x = pv[mt][wt][0] * inv;
            o.y = pv[mt][wt][1] * inv;
            o.z = pv[mt][wt][2] * inv;
            o.w = pv[mt][wt][3] * inv;
            *(float4*)(op + mt * 16 + g * 4) = o;
        }
    }
}

extern "C" void kernel_launch(void* const* d_in, const int* in_sizes, int n_in,
                              void* d_out, int out_size, void* d_ws, size_t ws_size,
                              hipStream_t stream)
{
    const float* x      = (const float*)d_in[0];   // [64,512,256]
    const float* w_qkv  = (const float*)d_in[1];   // [768,256]
    const float* w_proj = (const float*)d_in[2];   // [256,256]
    const float* b_proj = (const float*)d_in[3];   // [256]
    float* out = (float*)d_out;                    // [64,512,256]

    float* qkv  = (float*)d_ws;                    // [32768][768]
    float* attn = qkv + (size_t)32768 * 768;       // [32768][256]

    const int M = 32768;

    // 1) qkv = x @ w_qkv^T   (bf16x3 MFMA)
    gemm_nt_mfma<<<dim3(768 / 64, M / 64), 256, 0, stream>>>(x, w_qkv, nullptr, qkv, M, 768);

    // 2) local-window attention (MFMA)
    attn_local_mfma<<<dim3(8, 64), 512, 0, stream>>>(qkv, attn);

    // 3) out = attn @ w_proj^T + b_proj   (bf16x3 MFMA)
    gemm_nt_mfma<<<dim3(256 / 64, M / 64), 256, 0, stream>>>(attn, w_proj, b_proj, out, M, 256);
}